// Round 12
// baseline (169.675 us; speedup 1.0000x reference)
//
#include <hip/hip_runtime.h>
#include <math.h>

typedef unsigned short ushort_t;
typedef __attribute__((ext_vector_type(8))) __bf16 bf16x8;
typedef __attribute__((ext_vector_type(4))) float floatx4;

#define B_    256
#define I_    1152
#define J_    10
#define DIN_  8
#define DOUT_ 16
#define K_    (I_*DIN_)     // 9216
#define N_    (J_*DOUT_)    // 160
#define WPS   16            // waves per block = in-block split-K (monolith)
#define KCHUNK (K_/WPS)     // 576 (72 i's per wave)
#define KSTEPS (KCHUNK/32)  // 18
#define CHUNK16 2368        // 37KB packed chunk stride in 16B units

static __device__ __forceinline__ ushort_t f2bf(float f) {
    unsigned int u = __float_as_uint(f);
    u += 0x7fffu + ((u >> 16) & 1u);     // RNE
    return (ushort_t)(u >> 16);
}
static __device__ __forceinline__ float bf2f(ushort_t h) {
    return __uint_as_float(((unsigned int)h) << 16);
}

// ---------------------------------------------------------------------------
// D1: prep ∪ iter-0 s-GEMM monolith. Round-27 structure: the session's data
// says the ~135us floor is the 9-dispatch serial chain (~10us launch+drain
// each), not the kernels (every intra-kernel theory r3..r11 was null).
// Blocks 0..287: x -> xPk (fragment-major Dekker bf16 hi/lo; bit-identical
// splits). Blocks 288..647: W -> wPk (fp32 permuted copy). Blocks 648..807:
// r0's VERIFIED gemm_s monolith (original x/W, cs=0.1, in-block 16-wave
// split-K + squash + Sbt emit) — independent of prep, so they share D1.
// ---------------------------------------------------------------------------
__global__ __launch_bounds__(1024)
void prep_and_gemm0_kernel(const float* __restrict__ x, const float* __restrict__ W,
                           ushort_t* __restrict__ xPk, float* __restrict__ wPk,
                           ushort_t* __restrict__ Sbt_hi, ushort_t* __restrict__ Sbt_lo)
{
    const int blk = blockIdx.x;
    const int tid = threadIdx.x;

    __shared__ floatx4 part[WPS * 64];     // used by gemm role only (16 KB)

    if (blk < 288) {
        // ---- x-pack: gid over [0, 294912) ----
        const int gid = blk * 1024 + tid;
        const int f   = gid * 8;
        const int row = f / K_;
        const int kk  = f - row * K_;
        const int kc  = kk / KCHUNK;
        const int t   = kk - kc * KCHUNK;
        const int s   = t >> 5;
        const int q   = (t & 31) >> 3;
        const int mb  = row >> 4, r = row & 15;

        const float* src = x + (size_t)f;
        bf16x8 h8, l8;
        #pragma unroll
        for (int e = 0; e < 8; ++e) {
            float v = src[e];
            __bf16 h = (__bf16)v;
            h8[e] = h;
            l8[e] = (__bf16)(v - (float)h);
        }
        bf16x8* dst = (bf16x8*)xPk + (size_t)(mb * 16 + kc) * CHUNK16 + s * 128 + q * 16 + r;
        dst[0]  = h8;
        dst[64] = l8;
        return;
    }
    if (blk < 648) {
        // ---- W-pack: gid over [0, 368640) ----
        const int gid = (blk - 288) * 1024 + tid;
        const int f   = gid * 4;
        const int i   = f / 1280;
        const int rem = f - i * 1280;
        const int no  = rem >> 3;
        const int p   = (rem >> 2) & 1;
        const int nt  = no >> 4, r = no & 15;
        const int kc  = i / 72;
        const int m   = i - kc * 72;
        const int s   = m >> 2, q = m & 3;
        float4 v = *(const float4*)(W + (size_t)f);
        ((float4*)wPk)[(size_t)(nt * 16 + kc) * CHUNK16 + (s * 2 + p) * 64 + q * 16 + r] = v;
        return;
    }

    // ---- iter-0 s-GEMM monolith (r0 body verbatim, iter==0 path) ----
    const int blk_ = blk - 648;            // 0..159
    const int xcd  = blk_ & 7;
    const int sl   = blk_ >> 3;
    const int mb   = (xcd >> 1) * 4 + (sl & 3);
    const int nt   = (xcd & 1) * 5 + (sl >> 2);
    const int lane = tid & 63;
    const int w    = tid >> 6;             // wave = k-split 0..15

    {
        const int r = lane & 15, q = lane >> 4;
        const float* ap = x + (size_t)(mb * 16 + r) * K_ + w * KCHUNK + 8 * q;
        const float* wp = W + (((size_t)(w * 72 + q) * J_ + nt) * DOUT_ + r) * DIN_;
        const size_t wstep = (size_t)4 * J_ * DOUT_ * DIN_;
        floatx4 acc = {0.f, 0.f, 0.f, 0.f};

        float4 xa0 = *(const float4*)(ap);
        float4 xa1 = *(const float4*)(ap + 4);
        float4 w0  = *(const float4*)(wp);
        float4 w1  = *(const float4*)(wp + 4);
        #pragma unroll
        for (int s = 0; s < KSTEPS; ++s) {
            float4 nxa0, nxa1, nw0, nw1;
            if (s + 1 < KSTEPS) {
                nxa0 = *(const float4*)(ap + (s + 1) * 32);
                nxa1 = *(const float4*)(ap + (s + 1) * 32 + 4);
                nw0  = *(const float4*)(wp + (s + 1) * wstep);
                nw1  = *(const float4*)(wp + (s + 1) * wstep + 4);
            }
            const float cs = 0.1f;         // iter 0: softmax of zero logits
            float xv[8]  = {xa0.x, xa0.y, xa0.z, xa0.w, xa1.x, xa1.y, xa1.z, xa1.w};
            float wvv[8] = {w0.x, w0.y, w0.z, w0.w, w1.x, w1.y, w1.z, w1.w};
            bf16x8 ah, al, bh, bl;
            #pragma unroll
            for (int e = 0; e < 8; ++e) {
                float xe = xv[e];
                __bf16 h = (__bf16)xe;
                ah[e] = h;
                al[e] = (__bf16)(xe - (float)h);
                float pe = wvv[e] * cs;
                __bf16 g = (__bf16)pe;
                bh[e] = g;
                bl[e] = (__bf16)(pe - (float)g);
            }
            acc = __builtin_amdgcn_mfma_f32_16x16x32_bf16(ah, bh, acc, 0, 0, 0);
            acc = __builtin_amdgcn_mfma_f32_16x16x32_bf16(al, bh, acc, 0, 0, 0);
            acc = __builtin_amdgcn_mfma_f32_16x16x32_bf16(ah, bl, acc, 0, 0, 0);
            if (s + 1 < KSTEPS) { xa0 = nxa0; xa1 = nxa1; w0 = nw0; w1 = nw1; }
        }
        part[w * 64 + lane] = acc;
    }
    __syncthreads();

    if (tid < 256) {
        const int b_local = tid >> 4;
        const int o       = tid & 15;
        const int lane_c  = ((b_local >> 2) << 4) | o;
        const int reg     = b_local & 3;
        float v = 0.f;
        #pragma unroll
        for (int u = 0; u < WPS; ++u)
            v += part[u * 64 + lane_c][reg];
        float sq = v * v;
        #pragma unroll
        for (int off = 1; off < 16; off <<= 1)
            sq += __shfl_xor(sq, off, 16);
        float l2 = sqrtf(sq);
        float val = v * (l2 / (1.f + sq));
        const int b  = mb * 16 + b_local;
        const int jo = nt * 16 + o;
        ushort_t hi = f2bf(val);
        Sbt_hi[(size_t)jo * B_ + b] = hi;
        Sbt_lo[(size_t)jo * B_ + b] = f2bf(val - bf2f(hi));
    }
}

// ---------------------------------------------------------------------------
// D3/D5: s-GEMM monolith for iters 1,2 — r0 skeleton (160x1024, in-block
// split-K, full softmax, r0 epilogue) with the K-loop fed by PACKED operands
// (r7's verified pure load+MFMA loop; wave w = chunk kc=w). Zero in-loop
// VALU on the x side; cs*W Dekker in-loop (identical values to r0/r7).
// ---------------------------------------------------------------------------
__global__ __launch_bounds__(1024)
void gemm_s_fused_pk_kernel(const ushort_t* __restrict__ xPk, const float* __restrict__ wPk,
                            const float* __restrict__ blog, float* __restrict__ s_out,
                            ushort_t* __restrict__ Sbt_hi, ushort_t* __restrict__ Sbt_lo,
                            const int iter)
{
    const int tid  = threadIdx.x;          // 0..1023
    const int blk  = blockIdx.x;           // 0..159
    const int xcd  = blk & 7;
    const int sl   = blk >> 3;
    const int mb   = (xcd >> 1) * 4 + (sl & 3);
    const int nt   = (xcd & 1) * 5 + (sl >> 2);
    const int lane = tid & 63;
    const int w    = tid >> 6;             // wave = k-chunk 0..15

    __shared__ float   c_lds[I_];          // 4.6 KB
    __shared__ floatx4 part[WPS * 64];     // 16 KB

    {   // softmax(blog) rows -> c[i][nt]   (iter >= 1 always here)
        for (int r2 = tid; r2 < I_; r2 += 1024) {
            const float* br = blog + (size_t)r2 * J_;
            float bv[J_];
            float mx = -1e30f;
            #pragma unroll
            for (int j = 0; j < J_; ++j) { bv[j] = br[j]; mx = fmaxf(mx, bv[j]); }
            float sum = 0.f;
            #pragma unroll
            for (int j = 0; j < J_; ++j) { bv[j] = __expf(bv[j] - mx); sum += bv[j]; }
            c_lds[r2] = bv[nt] / sum;
        }
        __syncthreads();
    }

    {
        const int q = lane >> 4;
        const bf16x8* xp = (const bf16x8*)xPk + (size_t)(mb * 16 + w) * CHUNK16 + lane;
        const float4* wp = (const float4*)wPk + (size_t)(nt * 16 + w) * CHUNK16 + lane;
        floatx4 acc = {0.f, 0.f, 0.f, 0.f};

        bf16x8 rah[2], ral[2];
        float4 rw0[2], rw1[2];
        #pragma unroll
        for (int s = 0; s < 2; ++s) {
            rah[s] = xp[s * 128];
            ral[s] = xp[s * 128 + 64];
            rw0[s] = wp[s * 128];
            rw1[s] = wp[s * 128 + 64];
        }
        #pragma unroll
        for (int s = 0; s < KSTEPS; ++s) {
            bf16x8 ah = rah[s & 1], al = ral[s & 1];
            float4 w0 = rw0[s & 1], w1 = rw1[s & 1];
            if (s + 2 < KSTEPS) {
                rah[s & 1] = xp[(s + 2) * 128];
                ral[s & 1] = xp[(s + 2) * 128 + 64];
                rw0[s & 1] = wp[(s + 2) * 128];
                rw1[s & 1] = wp[(s + 2) * 128 + 64];
            }
            float cs = c_lds[w * 72 + 4 * s + q];
            float wvv[8] = {w0.x, w0.y, w0.z, w0.w, w1.x, w1.y, w1.z, w1.w};
            bf16x8 bh, bl;
            #pragma unroll
            for (int e = 0; e < 8; ++e) {
                float pe = wvv[e] * cs;
                __bf16 g = (__bf16)pe;
                bh[e] = g;
                bl[e] = (__bf16)(pe - (float)g);
            }
            acc = __builtin_amdgcn_mfma_f32_16x16x32_bf16(ah, bh, acc, 0, 0, 0);
            acc = __builtin_amdgcn_mfma_f32_16x16x32_bf16(al, bh, acc, 0, 0, 0);
            acc = __builtin_amdgcn_mfma_f32_16x16x32_bf16(ah, bl, acc, 0, 0, 0);
        }
        part[w * 64 + lane] = acc;
    }
    __syncthreads();

    if (tid < 256) {                       // r0 epilogue verbatim
        const int b_local = tid >> 4;
        const int o       = tid & 15;
        const int lane_c  = ((b_local >> 2) << 4) | o;
        const int reg     = b_local & 3;
        float v = 0.f;
        #pragma unroll
        for (int u = 0; u < WPS; ++u)
            v += part[u * 64 + lane_c][reg];
        float sq = v * v;
        #pragma unroll
        for (int off = 1; off < 16; off <<= 1)
            sq += __shfl_xor(sq, off, 16);
        float l2 = sqrtf(sq);
        float val = v * (l2 / (1.f + sq));
        const int b  = mb * 16 + b_local;
        const int jo = nt * 16 + o;
        if (iter == 2) {
            s_out[(size_t)b * N_ + jo] = val;
        } else {
            ushort_t hi = f2bf(val);
            Sbt_hi[(size_t)jo * B_ + b] = hi;
            Sbt_lo[(size_t)jo * B_ + b] = f2bf(val - bf2f(hi));
        }
    }
}

// ---------------------------------------------------------------------------
// b-update GEMM (unchanged r5/r7/r11 — plain loads/stores only).
// ---------------------------------------------------------------------------
__global__ __launch_bounds__(256)
void gemm_bupd_kernel(const float* __restrict__ x,
                      const ushort_t* __restrict__ Sbt_hi, const ushort_t* __restrict__ Sbt_lo,
                      const float* __restrict__ W, float* __restrict__ blog,
                      const int first)
{
    int wv   = (blockIdx.x & 7) * 360 + (blockIdx.x >> 3) * 4 + (threadIdx.x >> 6);
    int lane = threadIdx.x & 63;
    int mt = wv / 5;
    int jp = wv - mt * 5;
    int j0 = jp * 2, j1 = jp * 2 + 1;
    int r = lane & 15, q = lane >> 4;
    const float* xp = x + (size_t)(8 * q) * K_ + (mt * 16 + r);
    size_t b0off = (size_t)(j0 * 16 + r) * B_ + 8 * q;
    size_t b1off = (size_t)(j1 * 16 + r) * B_ + 8 * q;
    floatx4 acc0 = {0.f, 0.f, 0.f, 0.f};
    floatx4 acc1 = {0.f, 0.f, 0.f, 0.f};

    float xcur[8], xnxt[8];
    #pragma unroll
    for (int e = 0; e < 8; ++e) xcur[e] = xp[(size_t)e * K_];
    #pragma unroll
    for (int s = 0; s < B_ / 32; ++s) {
        if (s + 1 < B_ / 32) {
            #pragma unroll
            for (int e = 0; e < 8; ++e)
                xnxt[e] = xp[(size_t)((s + 1) * 32 + e) * K_];
        }
        bf16x8 ah, al;
        #pragma unroll
        for (int e = 0; e < 8; ++e) {
            float v = xcur[e];
            __bf16 h = (__bf16)v;
            ah[e] = h;
            al[e] = (__bf16)(v - (float)h);
        }
        bf16x8 bh0 = *(const bf16x8*)(Sbt_hi + b0off + s * 32);
        bf16x8 bl0 = *(const bf16x8*)(Sbt_lo + b0off + s * 32);
        bf16x8 bh1 = *(const bf16x8*)(Sbt_hi + b1off + s * 32);
        bf16x8 bl1 = *(const bf16x8*)(Sbt_lo + b1off + s * 32);
        acc0 = __builtin_amdgcn_mfma_f32_16x16x32_bf16(ah, bh0, acc0, 0, 0, 0);
        acc0 = __builtin_amdgcn_mfma_f32_16x16x32_bf16(al, bh0, acc0, 0, 0, 0);
        acc0 = __builtin_amdgcn_mfma_f32_16x16x32_bf16(ah, bl0, acc0, 0, 0, 0);
        acc1 = __builtin_amdgcn_mfma_f32_16x16x32_bf16(ah, bh1, acc1, 0, 0, 0);
        acc1 = __builtin_amdgcn_mfma_f32_16x16x32_bf16(al, bh1, acc1, 0, 0, 0);
        acc1 = __builtin_amdgcn_mfma_f32_16x16x32_bf16(ah, bl1, acc1, 0, 0, 0);
        #pragma unroll
        for (int e = 0; e < 8; ++e) xcur[e] = xnxt[e];
    }
    int i  = mt * 2 + (q >> 1);
    int d0 = (q & 1) * 4;
    int o  = lane & 15;
    int iw = mt * 2 + (lane >> 5);
    {
        const float4 w4 = *(const float4*)(W + ((((size_t)i * J_ + j0) * DOUT_ + o) * DIN_ + d0));
        float val = acc0[0] * w4.x + acc0[1] * w4.y + acc0[2] * w4.z + acc0[3] * w4.w;
        #pragma unroll
        for (int off = 1; off < 32; off <<= 1)
            val += __shfl_xor(val, off, 32);
        if ((lane & 31) == 0) {
            float* dst = blog + (size_t)iw * J_ + j0;
            if (first) *dst = val; else *dst += val;
        }
    }
    {
        const float4 w4 = *(const float4*)(W + ((((size_t)i * J_ + j1) * DOUT_ + o) * DIN_ + d0));
        float val = acc1[0] * w4.x + acc1[1] * w4.y + acc1[2] * w4.z + acc1[3] * w4.w;
        #pragma unroll
        for (int off = 1; off < 32; off <<= 1)
            val += __shfl_xor(val, off, 32);
        if ((lane & 31) == 0) {
            float* dst = blog + (size_t)iw * J_ + j1;
            if (first) *dst = val; else *dst += val;
        }
    }
}

// ---------------------------------------------------------------------------
// 5-dispatch chain (was 9): [prep ∪ A0B0], C0, A1B1, C1, A2B2.
// ---------------------------------------------------------------------------
extern "C" void kernel_launch(void* const* d_in, const int* in_sizes, int n_in,
                              void* d_out, int out_size, void* d_ws, size_t ws_size,
                              hipStream_t stream)
{
    const float* x = (const float*)d_in[0];   // [B, I, DIN]
    const float* W = (const float*)d_in[1];   // [I, J, DOUT, DIN]
    float* s_out = (float*)d_out;             // [B, J, DOUT]

    char* ws = (char*)d_ws;
    ushort_t* Sbt_hi = (ushort_t*)(ws);                 //    81,920 B
    ushort_t* Sbt_lo = (ushort_t*)(ws + 81920);         //    81,920 B
    float*    blog   = (float*)   (ws + 163840);        //    46,080 B
    ushort_t* xPk    = (ushort_t*)(ws + 262144);        // 9,699,328 B
    float*    wPk    = (float*)   (ws + 9961472);       // 6,062,080 B (~16 MB)

    prep_and_gemm0_kernel<<<808, 1024, 0, stream>>>(x, W, xPk, wPk,
                                                    Sbt_hi, Sbt_lo);
    gemm_bupd_kernel<<<720, 256, 0, stream>>>(x, Sbt_hi, Sbt_lo, W, blog, 1);
    gemm_s_fused_pk_kernel<<<160, 1024, 0, stream>>>(xPk, wPk, blog, s_out,
                                                     Sbt_hi, Sbt_lo, 1);
    gemm_bupd_kernel<<<720, 256, 0, stream>>>(x, Sbt_hi, Sbt_lo, W, blog, 0);
    gemm_s_fused_pk_kernel<<<160, 1024, 0, stream>>>(xPk, wPk, blog, s_out,
                                                     Sbt_hi, Sbt_lo, 2);
}

// Round 13
// 140.594 us; speedup vs baseline: 1.2068x; 1.2068x over previous
//
#include <hip/hip_runtime.h>
#include <math.h>

typedef unsigned short ushort_t;
typedef __attribute__((ext_vector_type(8))) __bf16 bf16x8;
typedef __attribute__((ext_vector_type(4))) float floatx4;

#define B_    256
#define I_    1152
#define J_    10
#define DIN_  8
#define DOUT_ 16
#define K_    (I_*DIN_)     // 9216
#define N_    (J_*DOUT_)    // 160
#define KSPLIT 16           // packed k-chunks per output tile
#define KCHUNK (K_/KSPLIT)  // 576
#define KSTEPS (KCHUNK/32)  // 18
#define CHUNK16 2368        // 37KB packed chunk stride in 16B units

static __device__ __forceinline__ ushort_t f2bf(float f) {
    unsigned int u = __float_as_uint(f);
    u += 0x7fffu + ((u >> 16) & 1u);     // RNE
    return (ushort_t)(u >> 16);
}
static __device__ __forceinline__ float bf2f(ushort_t h) {
    return __uint_as_float(((unsigned int)h) << 16);
}
// Relaxed agent-scope (LLC) atomics — r10-validated correct for cross-block
// handoff without fences; cheap at this volume (1.3 MB + 160 tickets).
static __device__ __forceinline__ void ast_f(float* p, float v) {
    __hip_atomic_store(p, v, __ATOMIC_RELAXED, __HIP_MEMORY_SCOPE_AGENT);
}
static __device__ __forceinline__ float ald_f(const float* p) {
    return __hip_atomic_load(p, __ATOMIC_RELAXED, __HIP_MEMORY_SCOPE_AGENT);
}

// ---------------------------------------------------------------------------
// Shared A+B epilogue: in-block 4-wave reduce -> LLC partial store -> ticket
// (NO fences; __syncthreads drains vmcnt, r4/r10-validated ordering) ->
// 8th-arriving block sums partials (r11 reduce order), squashes, emits.
// ---------------------------------------------------------------------------
static __device__ __forceinline__
void ab_epilogue(float* __restrict__ pbuf_it, unsigned int* __restrict__ cnt_it,
                 float* __restrict__ s_out, ushort_t* __restrict__ Sbt_hi,
                 ushort_t* __restrict__ Sbt_lo, const floatx4* part, int* last_s,
                 int tile, int kb, int mb, int nt, int tid, int it)
{
    const int row = tid >> 4;              // 0..15 (b_local)
    const int o   = tid & 15;              // 0..15
    const int lane_c = ((row >> 2) << 4) | o;   // C/D: col=lane&15, row=quad*4+reg
    const int reg    = row & 3;
    float v = part[0 * 64 + lane_c][reg] + part[1 * 64 + lane_c][reg]
            + part[2 * 64 + lane_c][reg] + part[3 * 64 + lane_c][reg];
    ast_f(pbuf_it + (size_t)(tile * 8 + kb) * 256 + row * 16 + o, v);
    __syncthreads();                       // drain stores (vmcnt) pre-ticket
    if (tid == 0)
        *last_s = (atomicAdd(cnt_it + tile, 1u) == 7u);
    __syncthreads();
    if (!*last_s) return;

    // ---- last arrival: sum 8 k-slice partials (r11 order), squash, emit ----
    const float* pb = pbuf_it + (size_t)tile * 8 * 256 + row * 16 + o;
    float vv = 0.f;
    #pragma unroll
    for (int u = 0; u < 8; ++u)
        vv += ald_f(pb + u * 256);
    float sq = vv * vv;
    #pragma unroll
    for (int off = 1; off < 16; off <<= 1)  // 16 consecutive lanes = one b row
        sq += __shfl_xor(sq, off, 16);
    float l2 = sqrtf(sq);
    float val = vv * (l2 / (1.f + sq));
    const int b  = mb * 16 + row;
    const int jo = nt * 16 + o;
    if (it == 2) {
        s_out[(size_t)b * N_ + jo] = val;
    } else {
        ushort_t hi = f2bf(val);
        Sbt_hi[(size_t)jo * B_ + b] = hi;
        Sbt_lo[(size_t)jo * B_ + b] = f2bf(val - bf2f(hi));
    }
}

// ---------------------------------------------------------------------------
// D1: [A0+B0 | xpack | wpack] — uniform 256-thr blocks, A0 FIRST in grid
// order (r12 lesson: the compute role must fill the machine immediately).
// A0 reads ORIGINAL x/W (independent of prep; cs=0.1; Dekker splits give
// values bit-identical to the packed path). r11 4-wave geometry.
// ---------------------------------------------------------------------------
__global__ __launch_bounds__(256)
void d1_kernel(const float* __restrict__ x, const float* __restrict__ W,
               ushort_t* __restrict__ xPk, float* __restrict__ wPk,
               float* __restrict__ pbuf, unsigned int* __restrict__ cnt,
               float* __restrict__ s_out,
               ushort_t* __restrict__ Sbt_hi, ushort_t* __restrict__ Sbt_lo)
{
    const int blk = blockIdx.x;
    const int tid = threadIdx.x;

    if (blk >= 1280) {
        if (blk < 2432) {
            // ---- xpack (r7 verbatim): gid over [0, 294912) ----
            const int gid = (blk - 1280) * 256 + tid;
            const int f   = gid * 8;
            const int row = f / K_;
            const int kk  = f - row * K_;
            const int kc  = kk / KCHUNK;
            const int t   = kk - kc * KCHUNK;
            const int s   = t >> 5;
            const int q   = (t & 31) >> 3;
            const int mb  = row >> 4, r = row & 15;
            const float* src = x + (size_t)f;
            bf16x8 h8, l8;
            #pragma unroll
            for (int e = 0; e < 8; ++e) {
                float v = src[e];
                __bf16 h = (__bf16)v;
                h8[e] = h;
                l8[e] = (__bf16)(v - (float)h);
            }
            bf16x8* dst = (bf16x8*)xPk + (size_t)(mb * 16 + kc) * CHUNK16 + s * 128 + q * 16 + r;
            dst[0]  = h8;
            dst[64] = l8;
        } else {
            // ---- wpack (r7 verbatim): gid over [0, 368640) ----
            const int gid = (blk - 2432) * 256 + tid;
            const int f   = gid * 4;
            const int i   = f / 1280;
            const int rem = f - i * 1280;
            const int no  = rem >> 3;
            const int p   = (rem >> 2) & 1;
            const int nt  = no >> 4, r = no & 15;
            const int kc  = i / 72;
            const int m   = i - kc * 72;
            const int s   = m >> 2, q = m & 3;
            float4 v = *(const float4*)(W + (size_t)f);
            ((float4*)wPk)[(size_t)(nt * 16 + kc) * CHUNK16 + (s * 2 + p) * 64 + q * 16 + r] = v;
        }
        return;
    }

    // ---- A0 role (blocks 0..1279): r11 geometry, original x/W, cs=0.1 ----
    const int kb    = blk & 7;
    const int tile  = blk >> 3;
    const int mb    = tile & 15;
    const int nt    = tile >> 4;
    const int lane  = tid & 63;
    const int w     = tid >> 6;            // 0..3
    const int kc    = kb * 2 + (w >> 1);
    const int sbase = (w & 1) * 9;         // 9-step half

    __shared__ floatx4 part[4 * 64];
    __shared__ int     last_s;

    {
        const int r = lane & 15, q = lane >> 4;
        const float* ap = x + (size_t)(mb * 16 + r) * K_ + kc * KCHUNK + 8 * q + sbase * 32;
        const float* wp = W + (((size_t)(kc * 72 + q) * J_ + nt) * DOUT_ + r) * DIN_;
        const size_t wstep = (size_t)4 * J_ * DOUT_ * DIN_;
        const float* wps = wp + sbase * wstep;
        floatx4 acc = {0.f, 0.f, 0.f, 0.f};

        float4 bxa0[2], bxa1[2], bw0[2], bw1[2];
        #pragma unroll
        for (int s = 0; s < 2; ++s) {
            bxa0[s] = *(const float4*)(ap + s * 32);
            bxa1[s] = *(const float4*)(ap + s * 32 + 4);
            bw0[s]  = *(const float4*)(wps + s * wstep);
            bw1[s]  = *(const float4*)(wps + s * wstep + 4);
        }
        #pragma unroll
        for (int s = 0; s < 9; ++s) {
            float4 xa0 = bxa0[s & 1], xa1 = bxa1[s & 1];
            float4 w0  = bw0[s & 1],  w1  = bw1[s & 1];
            if (s + 2 < 9) {
                bxa0[s & 1] = *(const float4*)(ap + (s + 2) * 32);
                bxa1[s & 1] = *(const float4*)(ap + (s + 2) * 32 + 4);
                bw0[s & 1]  = *(const float4*)(wps + (s + 2) * wstep);
                bw1[s & 1]  = *(const float4*)(wps + (s + 2) * wstep + 4);
            }
            const float cs = 0.1f;          // iter 0: softmax of zero logits
            float xv[8]  = {xa0.x, xa0.y, xa0.z, xa0.w, xa1.x, xa1.y, xa1.z, xa1.w};
            float wvv[8] = {w0.x, w0.y, w0.z, w0.w, w1.x, w1.y, w1.z, w1.w};
            bf16x8 ah, al, bh, bl;
            #pragma unroll
            for (int e = 0; e < 8; ++e) {
                float xe = xv[e];
                __bf16 h = (__bf16)xe;
                ah[e] = h;
                al[e] = (__bf16)(xe - (float)h);
                float pe = wvv[e] * cs;
                __bf16 g = (__bf16)pe;
                bh[e] = g;
                bl[e] = (__bf16)(pe - (float)g);
            }
            acc = __builtin_amdgcn_mfma_f32_16x16x32_bf16(ah, bh, acc, 0, 0, 0);
            acc = __builtin_amdgcn_mfma_f32_16x16x32_bf16(al, bh, acc, 0, 0, 0);
            acc = __builtin_amdgcn_mfma_f32_16x16x32_bf16(ah, bl, acc, 0, 0, 0);
        }
        part[w * 64 + lane] = acc;
    }
    __syncthreads();
    ab_epilogue(pbuf, cnt, s_out, Sbt_hi, Sbt_lo, part, &last_s,
                tile, kb, mb, nt, tid, 0);
}

// ---------------------------------------------------------------------------
// D2/D3 (iters 1,2): A+B merged — r11's packed 4-wave body + ticket epilogue.
// ---------------------------------------------------------------------------
__global__ __launch_bounds__(256)
void gemm_s_ab_kernel(const ushort_t* __restrict__ xPk, const float* __restrict__ wPk,
                      const float* __restrict__ blog,
                      float* __restrict__ pbuf, unsigned int* __restrict__ cnt,
                      float* __restrict__ s_out,
                      ushort_t* __restrict__ Sbt_hi, ushort_t* __restrict__ Sbt_lo,
                      const int iter)
{
    const int tid   = threadIdx.x;         // 0..255
    const int blk   = blockIdx.x;          // 0..1279
    const int kb    = blk & 7;
    const int tile  = blk >> 3;
    const int mb    = tile & 15;
    const int nt    = tile >> 4;
    const int lane  = tid & 63;
    const int w     = tid >> 6;            // 0..3
    const int kc    = kb * 2 + (w >> 1);
    const int shalf = w & 1;

    __shared__ float   c_lds[144];
    __shared__ floatx4 part[4 * 64];
    __shared__ int     last_s;

    {   // softmax(blog) rows for this kb slice (r11 verbatim)
        for (int r2 = tid; r2 < 144; r2 += 256) {
            const float* br = blog + (size_t)(kb * 144 + r2) * J_;
            float bv[J_];
            float mx = -1e30f;
            #pragma unroll
            for (int j = 0; j < J_; ++j) { bv[j] = br[j]; mx = fmaxf(mx, bv[j]); }
            float sum = 0.f;
            #pragma unroll
            for (int j = 0; j < J_; ++j) { bv[j] = __expf(bv[j] - mx); sum += bv[j]; }
            c_lds[r2] = bv[nt] / sum;
        }
        __syncthreads();
    }

    {
        const int q = lane >> 4;
        const int sbase = shalf * 9;
        const bf16x8* xp = (const bf16x8*)xPk + (size_t)(mb * 16 + kc) * CHUNK16
                           + sbase * 128 + lane;
        const float4* wp = (const float4*)wPk + (size_t)(nt * 16 + kc) * CHUNK16
                           + sbase * 128 + lane;
        floatx4 acc = {0.f, 0.f, 0.f, 0.f};

        bf16x8 rah[2], ral[2];
        float4 rw0[2], rw1[2];
        #pragma unroll
        for (int s = 0; s < 2; ++s) {
            rah[s] = xp[s * 128];
            ral[s] = xp[s * 128 + 64];
            rw0[s] = wp[s * 128];
            rw1[s] = wp[s * 128 + 64];
        }
        #pragma unroll
        for (int s = 0; s < 9; ++s) {
            bf16x8 ah = rah[s & 1], al = ral[s & 1];
            float4 w0 = rw0[s & 1], w1 = rw1[s & 1];
            if (s + 2 < 9) {
                rah[s & 1] = xp[(s + 2) * 128];
                ral[s & 1] = xp[(s + 2) * 128 + 64];
                rw0[s & 1] = wp[(s + 2) * 128];
                rw1[s & 1] = wp[(s + 2) * 128 + 64];
            }
            float cs = c_lds[(w >> 1) * 72 + 4 * (sbase + s) + q];
            float wvv[8] = {w0.x, w0.y, w0.z, w0.w, w1.x, w1.y, w1.z, w1.w};
            bf16x8 bh, bl;
            #pragma unroll
            for (int e = 0; e < 8; ++e) {
                float pe = wvv[e] * cs;
                __bf16 g = (__bf16)pe;
                bh[e] = g;
                bl[e] = (__bf16)(pe - (float)g);
            }
            acc = __builtin_amdgcn_mfma_f32_16x16x32_bf16(ah, bh, acc, 0, 0, 0);
            acc = __builtin_amdgcn_mfma_f32_16x16x32_bf16(al, bh, acc, 0, 0, 0);
            acc = __builtin_amdgcn_mfma_f32_16x16x32_bf16(ah, bl, acc, 0, 0, 0);
        }
        part[w * 64 + lane] = acc;
    }
    __syncthreads();
    ab_epilogue(pbuf, cnt, s_out, Sbt_hi, Sbt_lo, part, &last_s,
                tile, kb, mb, nt, tid, iter);
}

// ---------------------------------------------------------------------------
// b-update GEMM (unchanged r5/r7/r11 — plain loads/stores only).
// ---------------------------------------------------------------------------
__global__ __launch_bounds__(256)
void gemm_bupd_kernel(const float* __restrict__ x,
                      const ushort_t* __restrict__ Sbt_hi, const ushort_t* __restrict__ Sbt_lo,
                      const float* __restrict__ W, float* __restrict__ blog,
                      const int first)
{
    int wv   = (blockIdx.x & 7) * 360 + (blockIdx.x >> 3) * 4 + (threadIdx.x >> 6);
    int lane = threadIdx.x & 63;
    int mt = wv / 5;
    int jp = wv - mt * 5;
    int j0 = jp * 2, j1 = jp * 2 + 1;
    int r = lane & 15, q = lane >> 4;
    const float* xp = x + (size_t)(8 * q) * K_ + (mt * 16 + r);
    size_t b0off = (size_t)(j0 * 16 + r) * B_ + 8 * q;
    size_t b1off = (size_t)(j1 * 16 + r) * B_ + 8 * q;
    floatx4 acc0 = {0.f, 0.f, 0.f, 0.f};
    floatx4 acc1 = {0.f, 0.f, 0.f, 0.f};

    float xcur[8], xnxt[8];
    #pragma unroll
    for (int e = 0; e < 8; ++e) xcur[e] = xp[(size_t)e * K_];
    #pragma unroll
    for (int s = 0; s < B_ / 32; ++s) {
        if (s + 1 < B_ / 32) {
            #pragma unroll
            for (int e = 0; e < 8; ++e)
                xnxt[e] = xp[(size_t)((s + 1) * 32 + e) * K_];
        }
        bf16x8 ah, al;
        #pragma unroll
        for (int e = 0; e < 8; ++e) {
            float v = xcur[e];
            __bf16 h = (__bf16)v;
            ah[e] = h;
            al[e] = (__bf16)(v - (float)h);
        }
        bf16x8 bh0 = *(const bf16x8*)(Sbt_hi + b0off + s * 32);
        bf16x8 bl0 = *(const bf16x8*)(Sbt_lo + b0off + s * 32);
        bf16x8 bh1 = *(const bf16x8*)(Sbt_hi + b1off + s * 32);
        bf16x8 bl1 = *(const bf16x8*)(Sbt_lo + b1off + s * 32);
        acc0 = __builtin_amdgcn_mfma_f32_16x16x32_bf16(ah, bh0, acc0, 0, 0, 0);
        acc0 = __builtin_amdgcn_mfma_f32_16x16x32_bf16(al, bh0, acc0, 0, 0, 0);
        acc0 = __builtin_amdgcn_mfma_f32_16x16x32_bf16(ah, bl0, acc0, 0, 0, 0);
        acc1 = __builtin_amdgcn_mfma_f32_16x16x32_bf16(ah, bh1, acc1, 0, 0, 0);
        acc1 = __builtin_amdgcn_mfma_f32_16x16x32_bf16(al, bh1, acc1, 0, 0, 0);
        acc1 = __builtin_amdgcn_mfma_f32_16x16x32_bf16(ah, bl1, acc1, 0, 0, 0);
        #pragma unroll
        for (int e = 0; e < 8; ++e) xcur[e] = xnxt[e];
    }
    int i  = mt * 2 + (q >> 1);
    int d0 = (q & 1) * 4;
    int o  = lane & 15;
    int iw = mt * 2 + (lane >> 5);
    {
        const float4 w4 = *(const float4*)(W + ((((size_t)i * J_ + j0) * DOUT_ + o) * DIN_ + d0));
        float val = acc0[0] * w4.x + acc0[1] * w4.y + acc0[2] * w4.z + acc0[3] * w4.w;
        #pragma unroll
        for (int off = 1; off < 32; off <<= 1)
            val += __shfl_xor(val, off, 32);
        if ((lane & 31) == 0) {
            float* dst = blog + (size_t)iw * J_ + j0;
            if (first) *dst = val; else *dst += val;
        }
    }
    {
        const float4 w4 = *(const float4*)(W + ((((size_t)i * J_ + j1) * DOUT_ + o) * DIN_ + d0));
        float val = acc1[0] * w4.x + acc1[1] * w4.y + acc1[2] * w4.z + acc1[3] * w4.w;
        #pragma unroll
        for (int off = 1; off < 32; off <<= 1)
            val += __shfl_xor(val, off, 32);
        if ((lane & 31) == 0) {
            float* dst = blog + (size_t)iw * J_ + j1;
            if (first) *dst = val; else *dst += val;
        }
    }
}

// ---------------------------------------------------------------------------
// 6-dispatch chain (was 9): memset, [A0B0 ∥ prep], C0, A1B1, C1, A2B2.
// ---------------------------------------------------------------------------
extern "C" void kernel_launch(void* const* d_in, const int* in_sizes, int n_in,
                              void* d_out, int out_size, void* d_ws, size_t ws_size,
                              hipStream_t stream)
{
    const float* x = (const float*)d_in[0];   // [B, I, DIN]
    const float* W = (const float*)d_in[1];   // [I, J, DOUT, DIN]
    float* s_out = (float*)d_out;             // [B, J, DOUT]

    char* ws = (char*)d_ws;
    ushort_t*     Sbt_hi = (ushort_t*)(ws);                 //    81,920 B
    ushort_t*     Sbt_lo = (ushort_t*)(ws + 81920);         //    81,920 B
    float*        blog   = (float*)   (ws + 163840);        //    46,080 B
    float*        pbuf   = (float*)   (ws + 262144);        // 3,932,160 B (3 iters)
    ushort_t*     xPk    = (ushort_t*)(ws + 4194304);       // 9,699,328 B
    float*        wPk    = (float*)   (ws + 13893632);      // 6,062,080 B
    unsigned int* cnt    = (unsigned int*)(ws + 19955712);  //     1,920 B (~20 MB)

    (void)hipMemsetAsync(ws + 19955712, 0, 1920, stream);   // zero tickets

    // D1: A0+B0 (blocks 0..1279, original x/W) ∥ xpack (1280..2431) ∥ wpack
    d1_kernel<<<3872, 256, 0, stream>>>(x, W, xPk, wPk,
                                        pbuf, cnt, s_out, Sbt_hi, Sbt_lo);
    gemm_bupd_kernel<<<720, 256, 0, stream>>>(x, Sbt_hi, Sbt_lo, W, blog, 1);
    gemm_s_ab_kernel<<<1280, 256, 0, stream>>>(xPk, wPk, blog,
                                               pbuf + 327680, cnt + 160,
                                               s_out, Sbt_hi, Sbt_lo, 1);
    gemm_bupd_kernel<<<720, 256, 0, stream>>>(x, Sbt_hi, Sbt_lo, W, blog, 0);
    gemm_s_ab_kernel<<<1280, 256, 0, stream>>>(xPk, wPk, blog,
                                               pbuf + 655360, cnt + 320,
                                               s_out, Sbt_hi, Sbt_lo, 2);
}